// Round 11
// baseline (1011.330 us; speedup 1.0000x reference)
//
#include <hip/hip_runtime.h>
#include <cstdint>

typedef unsigned short u16;
typedef __attribute__((ext_vector_type(8))) short short8;   // 8 x bf16 (4 VGPR)
typedef __attribute__((ext_vector_type(4))) short short4v;  // 4 x bf16
typedef __attribute__((ext_vector_type(4))) float floatx4;  // MFMA acc / float4

#define DEV __device__ __forceinline__

DEV float bf2f(u16 u) { union { uint32_t i; float f; } w; w.i = ((uint32_t)u) << 16; return w.f; }
DEV u16 f2bf(float f) {
  union { float f; uint32_t i; } w; w.f = f;
  uint32_t x = w.i;
  return (u16)((x + 0x7fffu + ((x >> 16) & 1u)) >> 16);  // RNE
}

// fast exact-gelu: A&S 7.1.26 erf approx, |err|<=1.5e-7, branchless
DEV float fast_gelu(float x) {
  const float y = x * 0.70710678118f;
  const float ay = fabsf(y);
  const float t = 1.f / (1.f + 0.3275911f * ay);
  const float poly = t * (0.254829592f + t * (-0.284496736f +
                     t * (1.421413741f + t * (-1.453152027f + t * 1.061405429f))));
  const float er = 1.f - poly * __expf(-y * y);
  const float erf_y = __builtin_copysignf(er, y);
  return 0.5f * x * (1.f + erf_y);
}

// ---------------- fused f32 -> bf16 weight convert (all 10 weights) ----------------
struct CvtArgs {
  const float* src[10];
  float scale[10];
};
__global__ __launch_bounds__(256) void cvt_all(CvtArgs a, u16* __restrict__ dst) {
  const size_t e = ((size_t)blockIdx.x * 256 + threadIdx.x) * 4;  // 9437184 total elems
  if (e >= 9437184) return;
  int reg;
  size_t base;
  if (e < 4718592) { reg = (int)(e / 589824); base = (size_t)reg * 589824; }
  else if (e < 7077888) { reg = 8; base = 4718592; }
  else { reg = 9; base = 7077888; }
  const float sc = a.scale[reg];
  floatx4 f = *(const floatx4*)(a.src[reg] + (e - base));
  short4v o;
#pragma unroll
  for (int j = 0; j < 4; ++j) o[j] = (short)f2bf(f[j] * sc);
  *(short4v*)(dst + e) = o;
}

// pack q/k/v biases into one [2304] f32 buffer per stage, q part pre-scaled
__global__ __launch_bounds__(256) void bias_pack(const float* __restrict__ qb,
                                                 const float* __restrict__ kb,
                                                 const float* __restrict__ vb,
                                                 float sq, float* __restrict__ out) {
  const int i = blockIdx.x * 256 + threadIdx.x;
  if (i >= 2304) return;
  const int buf = i / 768, c = i - buf * 768;
  out[i] = buf == 0 ? qb[c] * sq : (buf == 1 ? kb[c] : vb[c]);
}

// ---------------- LayerNorm: one wave per row of 768, bf16 out ----------------
template<bool INF32>
__global__ __launch_bounds__(256) void ln_kernel(const void* __restrict__ in,
                                                 const float* __restrict__ w,
                                                 const float* __restrict__ b,
                                                 u16* __restrict__ out) {
  const int wid = threadIdx.x >> 6, lane = threadIdx.x & 63;
  const int row = blockIdx.x * 4 + wid;  // 16384 rows
  const size_t base = (size_t)row * 768;
  float v[12];
#pragma unroll
  for (int p = 0; p < 3; ++p) {
    const int e = p * 256 + lane * 4;
    if constexpr (INF32) {
      floatx4 f = *(const floatx4*)((const float*)in + base + e);
#pragma unroll
      for (int j = 0; j < 4; ++j) v[p * 4 + j] = f[j];
    } else {
      short4v u = *(const short4v*)((const u16*)in + base + e);
#pragma unroll
      for (int j = 0; j < 4; ++j) v[p * 4 + j] = bf2f((u16)u[j]);
    }
  }
  float s = 0.f, sq = 0.f;
#pragma unroll
  for (int i = 0; i < 12; ++i) { s += v[i]; sq += v[i] * v[i]; }
#pragma unroll
  for (int m = 1; m < 64; m <<= 1) { s += __shfl_xor(s, m); sq += __shfl_xor(sq, m); }
  const float mean = s * (1.f / 768.f);
  const float var = sq * (1.f / 768.f) - mean * mean;
  const float rstd = rsqrtf(var + 1e-5f);
#pragma unroll
  for (int p = 0; p < 3; ++p) {
    const int e = p * 256 + lane * 4;
    floatx4 wv = *(const floatx4*)(w + e);
    floatx4 bv = *(const floatx4*)(b + e);
    short4v o;
#pragma unroll
    for (int j = 0; j < 4; ++j) {
      float y = (v[p * 4 + j] - mean) * rstd * wv[j] + bv[j];
      o[j] = (short)f2bf(y);
    }
    *(short4v*)(out + base + e) = o;
  }
}

// ---------------- GEMM: C[M,N] = A[M,K] * B[N,K]^T (+epilogue) ----------------
// 128x128 tile, BK=32, 4 waves (2x2), mfma_f32_16x16x32_bf16.
// REG-STAGING: coalesced global loads (lane->(row,chunk) remap keeps 64B
// segments) -> ds_write_b128 into K-CHUNK-MAJOR LDS tile[c][row][8]:
//   - reads (16 lanes = rows 0..15, fixed chunk) span all 8 bank-quads -> 0 conflicts (proven r10)
//   - writes (8-lane groups = rows {0,2..14}+p) -> 4 quads x 2 lanes = 2-way (free)
// 2-buffer LDS (32KB), ping-pong reg sets, 1 raw barrier/iter; compiler emits
// counted vmcnt for the reg deps so next-next-tile loads stay in flight across
// the barrier. setprio around MFMA.
// AMODE: 0 = normal strides lda/ldb
//        2 = split-K row-attn logits: z = h*16+s, head h, K-window [s*384,+384)
//            elem(row,kk) = base + h*96 + (kk/96)*196608 + row*768 + (kk%96)
// EPI: 1 f32=acc | 2 bf16=gelu(acc+bz) | 3 f32=resf32+acc+bz | 4 bf16=resf32+acc+bz
//      5 f32=resbf16+acc+bz | 6 bf16=resbf16+acc+bz
//      7 bf16 scatter (row-attn PV): n=(r*96+d) -> out[(r*256+m)*768 + z*96 + d]
//      8 bf16 merged-QKV split write: buf=n/768 -> out + buf*12582912 + m*768 + (n%768)
template<int AMODE>
DEV const u16* gaddr(const u16* base, int row, int kk, int ld) {
  if constexpr (AMODE == 0) {
    return base + (size_t)row * ld + kk;
  } else {
    const int r96 = kk / 96, d = kk - r96 * 96;  // 8|96: chunk never crosses r96
    return base + (size_t)r96 * 196608 + (size_t)row * 768 + d;
  }
}

template<int AMODE, int EPI>
__global__ __launch_bounds__(256) void gemm_bt(
    const u16* __restrict__ A, const u16* __restrict__ B,
    const float* __restrict__ bias, const void* __restrict__ res,
    void* __restrict__ out, int K, int lda, int ldb,
    long long aBatch, long long bBatch, long long outBatch, int ldc, float scale) {
  __shared__ u16 lds[2 * 8192];  // 2 x (A 128x32 + B 128x32) = 32KB
  const int t = threadIdx.x;
  const int z = blockIdx.z;
  const int m0 = blockIdx.x * 128, n0 = blockIdx.y * 128;
  const u16* Ab;
  const u16* Bb;
  int koff = 0;
  if constexpr (AMODE == 0) { Ab = A + (size_t)z * aBatch; Bb = B + (size_t)z * bBatch; }
  else { const int h = z >> 4; Ab = A + h * 96; Bb = B + h * 96; koff = (z & 15) * 384; }

  const int wid = t >> 6, lane = t & 63;
  const int wr = wid >> 1, wc = wid & 1;
  const int lrow = lane & 15, lhi = lane >> 4;
  // staging lane remap: coalesced global (4 lanes/row cover 64B) AND 2-way LDS writes
  const int rA = ((lane & 7) << 1) | (lane >> 5);  // 0..15
  const int cc = (lane >> 3) & 3;                  // k-chunk 0..3
  const int rowL = wid * 16 + rA;                  // staging row, pass 0
  const int rowH = 64 + rowL;                      // staging row, pass 1

#define LOADT(d0, d1, d2, d3, kkv)                                         \
  {                                                                        \
    const int kq = (kkv) + cc * 8;                                         \
    d0 = *(const short8*)gaddr<AMODE>(Ab, m0 + rowL, kq, lda);             \
    d1 = *(const short8*)gaddr<AMODE>(Ab, m0 + rowH, kq, lda);             \
    d2 = *(const short8*)gaddr<AMODE>(Bb, n0 + rowL, kq, ldb);             \
    d3 = *(const short8*)gaddr<AMODE>(Bb, n0 + rowH, kq, ldb);             \
  }
#define WRITET(s0, s1, s2, s3, bi)                                         \
  {                                                                        \
    u16* dA = lds + (bi) * 8192;                                           \
    *(short8*)&dA[cc * 1024 + rowL * 8] = s0;                              \
    *(short8*)&dA[cc * 1024 + rowH * 8] = s1;                              \
    u16* dB = dA + 4096;                                                   \
    *(short8*)&dB[cc * 1024 + rowL * 8] = s2;                              \
    *(short8*)&dB[cc * 1024 + rowH * 8] = s3;                              \
  }
#define BARRIER()                                                          \
  asm volatile("s_waitcnt lgkmcnt(0)" ::: "memory");                       \
  __builtin_amdgcn_s_barrier();                                            \
  asm volatile("" ::: "memory");
#define COMPUTE(bi)                                                        \
  {                                                                        \
    const u16* lA = lds + (bi) * 8192;                                     \
    const u16* lB = lA + 4096;                                             \
    short8 af[4], bfr[4];                                                  \
    _Pragma("unroll") for (int mi = 0; mi < 4; ++mi)                       \
        af[mi] = *(const short8*)&lA[lhi * 1024 + (wr * 64 + mi * 16 + lrow) * 8]; \
    _Pragma("unroll") for (int ni = 0; ni < 4; ++ni)                       \
        bfr[ni] = *(const short8*)&lB[lhi * 1024 + (wc * 64 + ni * 16 + lrow) * 8]; \
    __builtin_amdgcn_s_setprio(1);                                         \
    _Pragma("unroll") for (int mi = 0; mi < 4; ++mi)                       \
        _Pragma("unroll") for (int ni = 0; ni < 4; ++ni)                   \
            acc[mi][ni] = __builtin_amdgcn_mfma_f32_16x16x32_bf16(af[mi], bfr[ni], acc[mi][ni], 0, 0, 0); \
    __builtin_amdgcn_s_setprio(0);                                         \
  }

  floatx4 acc[4][4];
#pragma unroll
  for (int i = 0; i < 4; ++i)
#pragma unroll
    for (int j = 0; j < 4; ++j) acc[i][j] = (floatx4){0.f, 0.f, 0.f, 0.f};

  const int NT = K >> 5;  // K/32 tiles; all our K give even NT >= 2

  short8 xa0, xa1, xb0, xb1, ya0, ya1, yb0, yb1;
  LOADT(xa0, xa1, xb0, xb1, koff);                 // tile 0 -> X
  if (NT > 1) LOADT(ya0, ya1, yb0, yb1, koff + 32);  // tile 1 -> Y
  WRITET(xa0, xa1, xb0, xb1, 0);                   // (compiler waits vmcnt for X)
  BARRIER();

  for (int kt = 0; kt < NT; kt += 2) {
    // even half: compute tile kt from buf0; Y holds kt+1; stage kt+2 -> X
    if (kt + 2 < NT) LOADT(xa0, xa1, xb0, xb1, koff + (kt + 2) * 32);
    {
      const u16* lA = lds;
      const u16* lB = lA + 4096;
      short8 af[4], bfr[4];
#pragma unroll
      for (int mi = 0; mi < 4; ++mi)
        af[mi] = *(const short8*)&lA[lhi * 1024 + (wr * 64 + mi * 16 + lrow) * 8];
#pragma unroll
      for (int ni = 0; ni < 4; ++ni)
        bfr[ni] = *(const short8*)&lB[lhi * 1024 + (wc * 64 + ni * 16 + lrow) * 8];
      WRITET(ya0, ya1, yb0, yb1, 1);  // tile kt+1 -> buf1 (compiler: counted vmcnt)
      __builtin_amdgcn_s_setprio(1);
#pragma unroll
      for (int mi = 0; mi < 4; ++mi)
#pragma unroll
        for (int ni = 0; ni < 4; ++ni)
          acc[mi][ni] = __builtin_amdgcn_mfma_f32_16x16x32_bf16(af[mi], bfr[ni], acc[mi][ni], 0, 0, 0);
      __builtin_amdgcn_s_setprio(0);
    }
    BARRIER();

    // odd half: compute tile kt+1 from buf1; X holds kt+2; stage kt+3 -> Y
    {
      const int ko = kt + 1;
      if (ko + 2 < NT) LOADT(ya0, ya1, yb0, yb1, koff + (ko + 2) * 32);
      const u16* lA = lds + 8192;
      const u16* lB = lA + 4096;
      short8 af[4], bfr[4];
#pragma unroll
      for (int mi = 0; mi < 4; ++mi)
        af[mi] = *(const short8*)&lA[lhi * 1024 + (wr * 64 + mi * 16 + lrow) * 8];
#pragma unroll
      for (int ni = 0; ni < 4; ++ni)
        bfr[ni] = *(const short8*)&lB[lhi * 1024 + (wc * 64 + ni * 16 + lrow) * 8];
      if (ko + 1 < NT) WRITET(xa0, xa1, xb0, xb1, 0);  // tile kt+2 -> buf0
      __builtin_amdgcn_s_setprio(1);
#pragma unroll
      for (int mi = 0; mi < 4; ++mi)
#pragma unroll
        for (int ni = 0; ni < 4; ++ni)
          acc[mi][ni] = __builtin_amdgcn_mfma_f32_16x16x32_bf16(af[mi], bfr[ni], acc[mi][ni], 0, 0, 0);
      __builtin_amdgcn_s_setprio(0);
      if (ko + 1 < NT) { BARRIER(); }
    }
  }
#undef LOADT
#undef WRITET
#undef BARRIER
#undef COMPUTE

  const int mbase = m0 + wr * 64;
  const int nbase = n0 + wc * 64;
#pragma unroll
  for (int mi = 0; mi < 4; ++mi) {
#pragma unroll
    for (int ni = 0; ni < 4; ++ni) {
      const int n = nbase + ni * 16 + lrow;
      float bz = 0.f;
      if constexpr (EPI != 1 && EPI != 7) { if (bias) bz = bias[n]; }
#pragma unroll
      for (int r4 = 0; r4 < 4; ++r4) {
        const int m = mbase + mi * 16 + lhi * 4 + r4;
        const float val = acc[mi][ni][r4];
        if constexpr (EPI == 1) {
          ((float*)out)[(size_t)z * outBatch + (size_t)m * ldc + n] = val;
        } else if constexpr (EPI == 2) {
          ((u16*)out)[(size_t)m * ldc + n] = f2bf(fast_gelu(val + bz));
        } else if constexpr (EPI == 3) {
          const float r = ((const float*)res)[(size_t)m * ldc + n];
          ((float*)out)[(size_t)m * ldc + n] = r + val + bz;
        } else if constexpr (EPI == 4) {
          const float r = ((const float*)res)[(size_t)m * ldc + n];
          ((u16*)out)[(size_t)m * ldc + n] = f2bf(r + val + bz);
        } else if constexpr (EPI == 5) {
          const float r = bf2f(((const u16*)res)[(size_t)m * ldc + n]);
          ((float*)out)[(size_t)m * ldc + n] = r + val + bz;
        } else if constexpr (EPI == 6) {
          const float r = bf2f(((const u16*)res)[(size_t)m * ldc + n]);
          ((u16*)out)[(size_t)m * ldc + n] = f2bf(r + val + bz);
        } else if constexpr (EPI == 7) {
          const int rr = n / 96, d = n - rr * 96;
          ((u16*)out)[((size_t)(rr * 256 + m)) * 768 + (size_t)z * 96 + d] = f2bf(val);
        } else if constexpr (EPI == 8) {
          const int buf = n / 768, col = n - buf * 768;
          ((u16*)out)[(size_t)buf * 12582912 + (size_t)m * 768 + col] = f2bf(val + bz);
        }
      }
    }
  }
}

// ---------------- row softmax fused with split-K reduce ----------------
__global__ __launch_bounds__(256) void softmax_row(const float* __restrict__ part,
                                                   float* __restrict__ probs_f,
                                                   u16* __restrict__ probs_b) {
  const int wid = threadIdx.x >> 6, lane = threadIdx.x & 63;
  const int row = blockIdx.x * 4 + wid;
  const int h = row >> 8, i = row & 255;
  const size_t base = (size_t)h * 16 * 65536 + (size_t)i * 256 + lane * 4;
  floatx4 v = (floatx4){0.f, 0.f, 0.f, 0.f};
#pragma unroll
  for (int s16 = 0; s16 < 16; ++s16) {
    floatx4 p = *(const floatx4*)(part + base + (size_t)s16 * 65536);
#pragma unroll
    for (int j = 0; j < 4; ++j) v[j] += p[j];
  }
  float mx = fmaxf(fmaxf(v[0], v[1]), fmaxf(v[2], v[3]));
#pragma unroll
  for (int m = 1; m < 64; m <<= 1) mx = fmaxf(mx, __shfl_xor(mx, m));
  float e[4], s = 0.f;
#pragma unroll
  for (int j = 0; j < 4; ++j) { e[j] = __expf(v[j] - mx); s += e[j]; }
#pragma unroll
  for (int m = 1; m < 64; m <<= 1) s += __shfl_xor(s, m);
  const float inv = 1.f / s;
  floatx4 of;
  short4v ob;
#pragma unroll
  for (int j = 0; j < 4; ++j) {
    const float p = e[j] * inv;
    of[j] = p;
    ob[j] = (short)f2bf(p);
  }
  *(floatx4*)(probs_f + (size_t)row * 256 + lane * 4) = of;
  *(short4v*)(probs_b + (size_t)row * 256 + lane * 4) = ob;
}

// ---------------- pack V^T for row-attn PV: vt[h][(r*96+d)][j] = v[(r*256+j)*768+h*96+d]
__global__ __launch_bounds__(256) void pack_vt(const u16* __restrict__ v, u16* __restrict__ vt) {
  __shared__ u16 S[64][104];  // [j][d], padded
  const int jb = blockIdx.x, r = blockIdx.y, h = blockIdx.z;
  const int t = threadIdx.x;
#pragma unroll
  for (int p = 0; p < 3; ++p) {
    const int cid = t + p * 256;
    const int j = cid / 12, ch = cid - j * 12;
    short8 x = *(const short8*)&v[((size_t)(r * 256 + jb * 64 + j)) * 768 + h * 96 + ch * 8];
    *(short8*)&S[j][ch * 8] = x;
  }
  __syncthreads();
#pragma unroll
  for (int p = 0; p < 3; ++p) {
    const int cid = t + p * 256;
    const int d = cid / 8, cj = cid - d * 8;
    u16 tmp[8];
#pragma unroll
    for (int m = 0; m < 8; ++m) tmp[m] = S[cj * 8 + m][d];
    *(short8*)&vt[((size_t)(h * 6144 + r * 96 + d)) * 256 + jb * 64 + cj * 8] = *(short8*)tmp;
  }
}

// ---------------- fused column attention: one block per (c, h) ----------------
__global__ __launch_bounds__(256) void col_attn(const u16* __restrict__ q,
                                                const u16* __restrict__ k,
                                                const u16* __restrict__ v,
                                                float* __restrict__ probs,
                                                u16* __restrict__ ctx) {
  __shared__ u16 qs[64][104];
  __shared__ u16 ks[64][104];
  __shared__ u16 vt[96][72];
  __shared__ u16 ps[64][72];
  const int c = blockIdx.x, h = blockIdx.y;
  const int t = threadIdx.x;
#pragma unroll
  for (int p = 0; p < 3; ++p) {
    const int cid = t + p * 256;
    const int i = cid / 12, ch = cid - i * 12;
    const size_t g = ((size_t)(i * 256 + c)) * 768 + h * 96 + ch * 8;
    short8 qv = *(const short8*)(q + g);
    short8 kv = *(const short8*)(k + g);
    short8 vv = *(const short8*)(v + g);
    *(short8*)&qs[i][ch * 8] = qv;
    *(short8*)&ks[i][ch * 8] = kv;
#pragma unroll
    for (int m = 0; m < 8; ++m) vt[ch * 8 + m][i] = (u16)vv[m];
  }
  __syncthreads();
  const int lane = t & 63, wid = t >> 6;
  const int lrow = lane & 15, lhi = lane >> 4;

  floatx4 s[4];
#pragma unroll
  for (int nj = 0; nj < 4; ++nj) s[nj] = (floatx4){0.f, 0.f, 0.f, 0.f};
#pragma unroll
  for (int kk = 0; kk < 3; ++kk) {
    short8 a = *(const short8*)&qs[wid * 16 + lrow][kk * 32 + lhi * 8];
#pragma unroll
    for (int nj = 0; nj < 4; ++nj) {
      short8 bb = *(const short8*)&ks[nj * 16 + lrow][kk * 32 + lhi * 8];
      s[nj] = __builtin_amdgcn_mfma_f32_16x16x32_bf16(a, bb, s[nj], 0, 0, 0);
    }
  }
  const size_t pb = ((size_t)(h * 256 + c)) * 4096;
#pragma unroll
  for (int r4 = 0; r4 < 4; ++r4) {
    float mx = fmaxf(fmaxf(s[0][r4], s[1][r4]), fmaxf(s[2][r4], s[3][r4]));
    mx = fmaxf(mx, __shfl_xor(mx, 1));
    mx = fmaxf(mx, __shfl_xor(mx, 2));
    mx = fmaxf(mx, __shfl_xor(mx, 4));
    mx = fmaxf(mx, __shfl_xor(mx, 8));
    float e[4], sum = 0.f;
#pragma unroll
    for (int nj = 0; nj < 4; ++nj) { e[nj] = __expf(s[nj][r4] - mx); sum += e[nj]; }
    sum += __shfl_xor(sum, 1);
    sum += __shfl_xor(sum, 2);
    sum += __shfl_xor(sum, 4);
    sum += __shfl_xor(sum, 8);
    const float inv = 1.f / sum;
    const int i = wid * 16 + lhi * 4 + r4;
#pragma unroll
    for (int nj = 0; nj < 4; ++nj) {
      const float pv = e[nj] * inv;
      const int j = nj * 16 + lrow;
      probs[pb + (size_t)i * 64 + j] = pv;
      ps[i][j] = f2bf(pv);
    }
  }
  __syncthreads();
  floatx4 o[6];
#pragma unroll
  for (int df = 0; df < 6; ++df) o[df] = (floatx4){0.f, 0.f, 0.f, 0.f};
#pragma unroll
  for (int k2 = 0; k2 < 2; ++k2) {
    short8 a = *(const short8*)&ps[wid * 16 + lrow][k2 * 32 + lhi * 8];
#pragma unroll
    for (int df = 0; df < 6; ++df) {
      short8 bb = *(const short8*)&vt[df * 16 + lrow][k2 * 32 + lhi * 8];
      o[df] = __builtin_amdgcn_mfma_f32_16x16x32_bf16(a, bb, o[df], 0, 0, 0);
    }
  }
#pragma unroll
  for (int df = 0; df < 6; ++df)
#pragma unroll
    for (int r4 = 0; r4 < 4; ++r4) {
      const int i = wid * 16 + lhi * 4 + r4;
      const int d = df * 16 + lrow;
      ctx[((size_t)(i * 256 + c)) * 768 + h * 96 + d] = f2bf(o[df][r4]);
    }
}

// ---------------- host launch ----------------
extern "C" void kernel_launch(void* const* d_in, const int* in_sizes, int n_in,
                              void* d_out, int out_size, void* d_ws, size_t ws_size,
                              hipStream_t stream) {
  const float* x_in  = (const float*)d_in[0];
  const float* lnr_w = (const float*)d_in[1];
  const float* lnr_b = (const float*)d_in[2];
  const float* rq_w  = (const float*)d_in[3];
  const float* rq_b  = (const float*)d_in[4];
  const float* rk_w  = (const float*)d_in[5];
  const float* rk_b  = (const float*)d_in[6];
  const float* rv_w  = (const float*)d_in[7];
  const float* rv_b  = (const float*)d_in[8];
  const float* ro_w  = (const float*)d_in[9];
  const float* ro_b  = (const float*)d_in[10];
  const float* lnc_w = (const float*)d_in[11];
  const float* lnc_b = (const float*)d_in[12];
  const float* cq_w  = (const float*)d_in[13];
  const float* cq_b  = (const float*)d_in[14];
  const float* ck_w  = (const float*)d_in[15];
  const float* ck_b  = (const float*)d_in[16];
  const float* cv_w  = (const float*)d_in[17];
  const float* cv_b  = (const float*)d_in[18];
  const float* co_w  = (const float*)d_in[19];
  const float* co_b  = (const float*)d_in[20];
  const float* lnf_w = (const float*)d_in[21];
  const float* lnf_b = (const float*)d_in[22];
  const float* f1_w  = (const float*)d_in[23];
  const float* f1_b  = (const float*)d_in[24];
  const float* f2_w  = (const float*)d_in[25];
  const float* f2_b  = (const float*)d_in[26];

  const float s_row = 0.0127577591f;  // (96^-0.5)/8
  const float s_col = 0.1020620726f;  // 96^-0.5

  // ---- ws layout ----
  char* ws = (char*)d_ws;
  const size_t WSZ_E = 589824 * 2;        // one E x E bf16 weight
  u16* w_all = (u16*)ws;                  // rq,rk,rv | ro | cq,ck,cv | co | f1 | f2
  u16* w_rqkv = w_all;
  u16* w_ro   = (u16*)(ws + 3 * WSZ_E);
  u16* w_cqkv = (u16*)(ws + 4 * WSZ_E);
  u16* w_co   = (u16*)(ws + 7 * WSZ_E);
  u16* w_f1   = (u16*)(ws + 8 * WSZ_E);                 // 4,718,592 B
  u16* w_f2   = (u16*)(ws + 8 * WSZ_E + 4718592);       // 4,718,592 B
  size_t off = 8 * WSZ_E + 2 * 4718592;                 // 18,874,368

  const bool xf32 = ws_size >= 147849216ULL;            // f32 residual if it fits
  char* x_cur = ws + off;                               // f32 (50.3MB) or bf16 (25.2MB)
  off += xf32 ? 50331648 : 25165824;
  u16* qb = (u16*)(ws + off); off += 25165824;
  u16* kb = (u16*)(ws + off); off += 25165824;
  u16* vb = (u16*)(ws + off); off += 25165824;
  u16* probsb = (u16*)(ws + off); off += 1048576;       // bf16 row probs
  float* qkvb_row = (float*)(ws + off); off += 9216;    // [2304] f32
  float* qkvb_col = (float*)(ws + off); off += 9216;

  u16* vt     = qb;            // row-attn V^T overlays qb (free after logits)
  u16* ctx1   = kb;            // row-attn context overlays kb
  u16* hidden = qb;            // FFN hidden chunk (50.3MB) overlays qb+kb
  u16* xn3    = vb;            // stage-3 LN output overlays vb

  // ---- d_out layout + d_out-as-scratch ----
  float* out_x  = (float*)d_out;            // 12,582,912 f32 (free until final fc2)
  float* out_rp = out_x + 12582912;         // row_probs [8,1,256,256] f32
  float* out_cp = out_x + 13107200;         // col_probs [8,256,1,64,64] f32
  u16* xn   = (u16*)out_x;                  // LN out (stages 1,2), lower half of out_x
  u16* ctx2 = (u16*)((char*)out_x + 25165824);  // col-attn context, upper half
  float* part = out_x;                      // split-K logits partials (33.5MB, dead after softmax)

  const dim3 blk(256);

  // ---- weight conversion (one dispatch) + bias packs ----
  CvtArgs ca;
  ca.src[0] = rq_w; ca.src[1] = rk_w; ca.src[2] = rv_w; ca.src[3] = ro_w;
  ca.src[4] = cq_w; ca.src[5] = ck_w; ca.src[6] = cv_w; ca.src[7] = co_w;
  ca.src[8] = f1_w; ca.src[9] = f2_w;
  for (int i = 0; i < 10; ++i) ca.scale[i] = 1.f;
  ca.scale[0] = s_row; ca.scale[4] = s_col;
  cvt_all<<<9216, blk, 0, stream>>>(ca, w_all);
  bias_pack<<<9, blk, 0, stream>>>(rq_b, rk_b, rv_b, s_row, qkvb_row);
  bias_pack<<<9, blk, 0, stream>>>(cq_b, ck_b, cv_b, s_col, qkvb_col);

  // ---- Stage 1: row attention ----
  ln_kernel<true><<<4096, blk, 0, stream>>>(x_in, lnr_w, lnr_b, xn);
  gemm_bt<0, 8><<<dim3(128, 18, 1), blk, 0, stream>>>(xn, w_rqkv, qkvb_row, nullptr, qb, 768, 768, 768, 0, 0, 0, 768, 1.f);
  // split-K logits: grid.z = h*16+s, partials into d_out scratch (xn is dead now)
  gemm_bt<2, 1><<<dim3(2, 2, 128), blk, 0, stream>>>(qb, kb, nullptr, nullptr, part, 384, 0, 0, 0, 0, 65536LL, 256, 1.f);
  softmax_row<<<512, blk, 0, stream>>>(part, out_rp, probsb);
  pack_vt<<<dim3(4, 64, 8), blk, 0, stream>>>(vb, vt);
  gemm_bt<0, 7><<<dim3(2, 48, 8), blk, 0, stream>>>(probsb, vt, nullptr, nullptr, ctx1, 256, 256, 256, 65536LL, 1572864LL, 0, 0, 1.f);
  if (xf32)
    gemm_bt<0, 3><<<dim3(128, 6, 1), blk, 0, stream>>>(ctx1, w_ro, ro_b, x_in, x_cur, 768, 768, 768, 0, 0, 0, 768, 1.f);
  else
    gemm_bt<0, 4><<<dim3(128, 6, 1), blk, 0, stream>>>(ctx1, w_ro, ro_b, x_in, x_cur, 768, 768, 768, 0, 0, 0, 768, 1.f);

  // ---- Stage 2: column attention ----
  if (xf32) ln_kernel<true><<<4096, blk, 0, stream>>>(x_cur, lnc_w, lnc_b, xn);
  else      ln_kernel<false><<<4096, blk, 0, stream>>>(x_cur, lnc_w, lnc_b, xn);
  gemm_bt<0, 8><<<dim3(128, 18, 1), blk, 0, stream>>>(xn, w_cqkv, qkvb_col, nullptr, qb, 768, 768, 768, 0, 0, 0, 768, 1.f);
  col_attn<<<dim3(256, 8), blk, 0, stream>>>(qb, kb, vb, out_cp, ctx2);
  if (xf32)
    gemm_bt<0, 3><<<dim3(128, 6, 1), blk, 0, stream>>>(ctx2, w_co, co_b, x_cur, x_cur, 768, 768, 768, 0, 0, 0, 768, 1.f);
  else
    gemm_bt<0, 6><<<dim3(128, 6, 1), blk, 0, stream>>>(ctx2, w_co, co_b, x_cur, x_cur, 768, 768, 768, 0, 0, 0, 768, 1.f);

  // ---- Stage 3: FFN (F chunked 2x1536 so hidden fits qb+kb) ----
  if (xf32) ln_kernel<true><<<4096, blk, 0, stream>>>(x_cur, lnf_w, lnf_b, xn3);
  else      ln_kernel<false><<<4096, blk, 0, stream>>>(x_cur, lnf_w, lnf_b, xn3);
  // chunk 0
  gemm_bt<0, 2><<<dim3(128, 12, 1), blk, 0, stream>>>(xn3, w_f1, f1_b, nullptr, hidden, 768, 768, 768, 0, 0, 0, 1536, 1.f);
  if (xf32)
    gemm_bt<0, 3><<<dim3(128, 6, 1), blk, 0, stream>>>(hidden, w_f2, f2_b, x_cur, out_x, 1536, 1536, 3072, 0, 0, 0, 768, 1.f);
  else
    gemm_bt<0, 5><<<dim3(128, 6, 1), blk, 0, stream>>>(hidden, w_f2, f2_b, x_cur, out_x, 1536, 1536, 3072, 0, 0, 0, 768, 1.f);
  // chunk 1 (accumulate into out_x)
  gemm_bt<0, 2><<<dim3(128, 12, 1), blk, 0, stream>>>(xn3, w_f1 + 1536 * 768, f1_b + 1536, nullptr, hidden, 768, 768, 768, 0, 0, 0, 1536, 1.f);
  gemm_bt<0, 3><<<dim3(128, 6, 1), blk, 0, stream>>>(hidden, w_f2 + 1536, nullptr, out_x, out_x, 1536, 1536, 3072, 0, 0, 0, 768, 1.f);
}

// Round 13
// 670.771 us; speedup vs baseline: 1.5077x; 1.5077x over previous
//
#include <hip/hip_runtime.h>
#include <cstdint>

typedef unsigned short u16;
typedef __attribute__((ext_vector_type(8))) short short8;   // 8 x bf16 (4 VGPR)
typedef __attribute__((ext_vector_type(4))) short short4v;  // 4 x bf16
typedef __attribute__((ext_vector_type(4))) float floatx4;  // MFMA acc / float4

#define DEV __device__ __forceinline__

DEV float bf2f(u16 u) { union { uint32_t i; float f; } w; w.i = ((uint32_t)u) << 16; return w.f; }
DEV u16 f2bf(float f) {
  union { float f; uint32_t i; } w; w.f = f;
  uint32_t x = w.i;
  return (u16)((x + 0x7fffu + ((x >> 16) & 1u)) >> 16);  // RNE
}

// fast exact-gelu: A&S 7.1.26 erf approx, |err|<=1.5e-7, branchless
DEV float fast_gelu(float x) {
  const float y = x * 0.70710678118f;
  const float ay = fabsf(y);
  const float t = 1.f / (1.f + 0.3275911f * ay);
  const float poly = t * (0.254829592f + t * (-0.284496736f +
                     t * (1.421413741f + t * (-1.453152027f + t * 1.061405429f))));
  const float er = 1.f - poly * __expf(-y * y);
  const float erf_y = __builtin_copysignf(er, y);
  return 0.5f * x * (1.f + erf_y);
}

// async global->LDS, 16B per lane. LDS dest must be wave-uniform base; HW adds lane*16.
DEV void async_copy16(const u16* g, u16* l) {
  __builtin_amdgcn_global_load_lds(
      (const __attribute__((address_space(1))) void*)(uintptr_t)g,
      (__attribute__((address_space(3))) void*)(uint32_t)(uintptr_t)l,
      16, 0, 0);
}

// ---------------- fused f32 -> bf16 weight convert (all 10 weights) ----------------
struct CvtArgs {
  const float* src[10];
  float scale[10];
};
__global__ __launch_bounds__(256) void cvt_all(CvtArgs a, u16* __restrict__ dst) {
  const size_t e = ((size_t)blockIdx.x * 256 + threadIdx.x) * 4;  // 9437184 total elems
  if (e >= 9437184) return;
  int reg;
  size_t base;
  if (e < 4718592) { reg = (int)(e / 589824); base = (size_t)reg * 589824; }
  else if (e < 7077888) { reg = 8; base = 4718592; }
  else { reg = 9; base = 7077888; }
  const float sc = a.scale[reg];
  floatx4 f = *(const floatx4*)(a.src[reg] + (e - base));
  short4v o;
#pragma unroll
  for (int j = 0; j < 4; ++j) o[j] = (short)f2bf(f[j] * sc);
  *(short4v*)(dst + e) = o;
}

// pack q/k/v biases into one [2304] f32 buffer per stage, q part pre-scaled
__global__ __launch_bounds__(256) void bias_pack(const float* __restrict__ qb,
                                                 const float* __restrict__ kb,
                                                 const float* __restrict__ vb,
                                                 float sq, float* __restrict__ out) {
  const int i = blockIdx.x * 256 + threadIdx.x;
  if (i >= 2304) return;
  const int buf = i / 768, c = i - buf * 768;
  out[i] = buf == 0 ? qb[c] * sq : (buf == 1 ? kb[c] : vb[c]);
}

// ---------------- LayerNorm: one wave per row of 768, bf16 out ----------------
template<bool INF32>
__global__ __launch_bounds__(256) void ln_kernel(const void* __restrict__ in,
                                                 const float* __restrict__ w,
                                                 const float* __restrict__ b,
                                                 u16* __restrict__ out) {
  const int wid = threadIdx.x >> 6, lane = threadIdx.x & 63;
  const int row = blockIdx.x * 4 + wid;  // 16384 rows
  const size_t base = (size_t)row * 768;
  float v[12];
#pragma unroll
  for (int p = 0; p < 3; ++p) {
    const int e = p * 256 + lane * 4;
    if constexpr (INF32) {
      floatx4 f = *(const floatx4*)((const float*)in + base + e);
#pragma unroll
      for (int j = 0; j < 4; ++j) v[p * 4 + j] = f[j];
    } else {
      short4v u = *(const short4v*)((const u16*)in + base + e);
#pragma unroll
      for (int j = 0; j < 4; ++j) v[p * 4 + j] = bf2f((u16)u[j]);
    }
  }
  float s = 0.f, sq = 0.f;
#pragma unroll
  for (int i = 0; i < 12; ++i) { s += v[i]; sq += v[i] * v[i]; }
#pragma unroll
  for (int m = 1; m < 64; m <<= 1) { s += __shfl_xor(s, m); sq += __shfl_xor(sq, m); }
  const float mean = s * (1.f / 768.f);
  const float var = sq * (1.f / 768.f) - mean * mean;
  const float rstd = rsqrtf(var + 1e-5f);
#pragma unroll
  for (int p = 0; p < 3; ++p) {
    const int e = p * 256 + lane * 4;
    floatx4 wv = *(const floatx4*)(w + e);
    floatx4 bv = *(const floatx4*)(b + e);
    short4v o;
#pragma unroll
    for (int j = 0; j < 4; ++j) {
      float y = (v[p * 4 + j] - mean) * rstd * wv[j] + bv[j];
      o[j] = (short)f2bf(y);
    }
    *(short4v*)(out + base + e) = o;
  }
}

// ---------------- GEMM: C[M,N] = A[M,K] * B[N,K]^T (+epilogue) ----------------
// 128x128 tile, BK=32, 4 waves (2x2), mfma_f32_16x16x32_bf16.
// 4-buffer LDS rotation, depth-3 prefetch, proven r8 ordering per iteration:
//   stage(kt+3) -> read frags(kt) + MFMA -> vmcnt(8/4/0) -> s_barrier
// The barrier AFTER the counted vmcnt publishes "tile kt+1 landed" to all
// waves (vmcnt is per-wave); stage(kt+3) targets buf (kt-1)&3 whose reads all
// completed before the previous end-of-iteration barrier.
// AMODE: 0 = normal strides lda/ldb
//        1 = row-attn logits addressing: elem(row,kk) = base + z*96 + (kk/96)*196608 + row*768 + (kk%96)
//        2 = split-K row-attn logits: z = h*16+s, head h, K-window [s*384, s*384+384)
// EPI: 1 f32=acc | 2 bf16=gelu(acc+bz) | 3 f32=resf32+acc+bz | 4 bf16=resf32+acc+bz
//      5 f32=resbf16+acc+bz | 6 bf16=resbf16+acc+bz
//      7 bf16 scatter (row-attn PV): n=(r*96+d) -> out[(r*256+m)*768 + z*96 + d]
//      8 bf16 merged-QKV split write: buf=n/768 -> out + buf*12582912 + m*768 + (n%768)
template<int AMODE>
DEV void stage_tile(const u16* __restrict__ Ab, const u16* __restrict__ Bb,
                    int m0, int n0, int lda, int ldb, int kk0, int t,
                    u16* ldsA, u16* ldsB) {
  const int wid = t >> 6;
  // swizzled source col: logical col stored at physical (t&3)*8 is ((t&3)^(r&3))*8
  const int col = (((t & 3) ^ ((t >> 2) & 3)) << 3);
#pragma unroll
  for (int i = 0; i < 2; ++i) {
    const int r = i * 64 + (t >> 2);
    const int kk = kk0 + col;
    const u16 *ga, *gb;
    if constexpr (AMODE == 0) {
      ga = Ab + (size_t)(m0 + r) * lda + kk;
      gb = Bb + (size_t)(n0 + r) * ldb + kk;
    } else {
      const int r96 = kk / 96, d = kk - r96 * 96;  // 8|96: chunk never crosses r96
      ga = Ab + (size_t)r96 * 196608 + (size_t)(m0 + r) * 768 + d;
      gb = Bb + (size_t)r96 * 196608 + (size_t)(n0 + r) * 768 + d;
    }
    async_copy16(ga, ldsA + i * 2048 + wid * 512);
    async_copy16(gb, ldsB + i * 2048 + wid * 512);
  }
}

template<int AMODE, int EPI>
__global__ __launch_bounds__(256) void gemm_bt(
    const u16* __restrict__ A, const u16* __restrict__ B,
    const float* __restrict__ bias, const void* __restrict__ res,
    void* __restrict__ out, int K, int lda, int ldb,
    long long aBatch, long long bBatch, long long outBatch, int ldc, float scale) {
  __shared__ u16 lds[4 * 8192];  // 4 x (A 128x32 + B 128x32) = 64KB
  const int t = threadIdx.x;
  const int z = blockIdx.z;
  const int m0 = blockIdx.x * 128, n0 = blockIdx.y * 128;
  const u16* Ab;
  const u16* Bb;
  int koff = 0;
  if constexpr (AMODE == 0) { Ab = A + (size_t)z * aBatch; Bb = B + (size_t)z * bBatch; }
  else if constexpr (AMODE == 1) { Ab = A + z * 96; Bb = B + z * 96; }
  else { const int h = z >> 4; Ab = A + h * 96; Bb = B + h * 96; koff = (z & 15) * 384; }

  const int wid = t >> 6, lane = t & 63;
  const int wr = wid >> 1, wc = wid & 1;
  const int lrow = lane & 15, lhi = lane >> 4;
  const int swl = lrow & 3;  // read-side swizzle key (matches stage-side col xor)

  floatx4 acc[4][4];
#pragma unroll
  for (int i = 0; i < 4; ++i)
#pragma unroll
    for (int j = 0; j < 4; ++j) acc[i][j] = (floatx4){0.f, 0.f, 0.f, 0.f};

  const int NT = K >> 5;  // K/32 tiles (all K are multiples of 32)

  // prologue: stage tiles 0..2 (depth-3), then publish tile 0
  stage_tile<AMODE>(Ab, Bb, m0, n0, lda, ldb, koff, t, lds, lds + 4096);
  if (NT > 1)
    stage_tile<AMODE>(Ab, Bb, m0, n0, lda, ldb, koff + 32, t, lds + 8192, lds + 8192 + 4096);
  if (NT > 2)
    stage_tile<AMODE>(Ab, Bb, m0, n0, lda, ldb, koff + 64, t, lds + 16384, lds + 16384 + 4096);
  if (NT > 2)      asm volatile("s_waitcnt vmcnt(8)" ::: "memory");
  else if (NT > 1) asm volatile("s_waitcnt vmcnt(4)" ::: "memory");
  else             asm volatile("s_waitcnt vmcnt(0)" ::: "memory");
  __builtin_amdgcn_s_barrier();
  asm volatile("" ::: "memory");

  for (int kt = 0; kt < NT; ++kt) {
    // stage(kt+3) -> buf (kt+3)&3 == (kt-1)&3: reads of it finished before the
    // previous end-of-iteration barrier, so write-after-read is safe.
    if (kt + 3 < NT) {
      const int nxt = (kt + 3) & 3;
      stage_tile<AMODE>(Ab, Bb, m0, n0, lda, ldb, koff + (kt + 3) * 32, t,
                        lds + nxt * 8192, lds + nxt * 8192 + 4096);
    }

    const u16* lA = lds + (kt & 3) * 8192;
    const u16* lB = lA + 4096;
    short8 af[4], bfr[4];
#pragma unroll
    for (int mi = 0; mi < 4; ++mi)
      af[mi] = *(const short8*)&lA[(wr * 64 + mi * 16 + lrow) * 32 + ((lhi ^ swl) << 3)];
#pragma unroll
    for (int ni = 0; ni < 4; ++ni)
      bfr[ni] = *(const short8*)&lB[(wc * 64 + ni * 16 + lrow) * 32 + ((lhi ^ swl) << 3)];

    __builtin_amdgcn_s_setprio(1);
#pragma unroll
    for (int mi = 0; mi < 4; ++mi)
#pragma unroll
      for (int ni = 0; ni < 4; ++ni)
        acc[mi][ni] = __builtin_amdgcn_mfma_f32_16x16x32_bf16(af[mi], bfr[ni], acc[mi][ni], 0, 0, 0);
    __builtin_amdgcn_s_setprio(0);

    if (kt + 1 < NT) {
      // wait until own tile-(kt+1) loads landed: outstanding <= stages kt+2,kt+3
      if (kt + 3 < NT)      asm volatile("s_waitcnt vmcnt(8)" ::: "memory");
      else if (kt + 2 < NT) asm volatile("s_waitcnt vmcnt(4)" ::: "memory");
      else                  asm volatile("s_waitcnt vmcnt(0)" ::: "memory");
      __builtin_amdgcn_s_barrier();  // publish to all waves
      asm volatile("" ::: "memory");
    }
  }

  const int mbase = m0 + wr * 64;
  const int nbase = n0 + wc * 64;
#pragma unroll
  for (int mi = 0; mi < 4; ++mi) {
#pragma unroll
    for (int ni = 0; ni < 4; ++ni) {
      const int n = nbase + ni * 16 + lrow;
      float bz = 0.f;
      if constexpr (EPI != 1 && EPI != 7) { if (bias) bz = bias[n]; }
#pragma unroll
      for (int r4 = 0; r4 < 4; ++r4) {
        const int m = mbase + mi * 16 + lhi * 4 + r4;
        const float val = acc[mi][ni][r4];
        if constexpr (EPI == 1) {
          ((float*)out)[(size_t)z * outBatch + (size_t)m * ldc + n] = val;
        } else if constexpr (EPI == 2) {
          ((u16*)out)[(size_t)m * ldc + n] = f2bf(fast_gelu(val + bz));
        } else if constexpr (EPI == 3) {
          const float r = ((const float*)res)[(size_t)m * ldc + n];
          ((float*)out)[(size_t)m * ldc + n] = r + val + bz;
        } else if constexpr (EPI == 4) {
          const float r = ((const float*)res)[(size_t)m * ldc + n];
          ((u16*)out)[(size_t)m * ldc + n] = f2bf(r + val + bz);
        } else if constexpr (EPI == 5) {
          const float r = bf2f(((const u16*)res)[(size_t)m * ldc + n]);
          ((float*)out)[(size_t)m * ldc + n] = r + val + bz;
        } else if constexpr (EPI == 6) {
          const float r = bf2f(((const u16*)res)[(size_t)m * ldc + n]);
          ((u16*)out)[(size_t)m * ldc + n] = f2bf(r + val + bz);
        } else if constexpr (EPI == 7) {
          const int rr = n / 96, d = n - rr * 96;
          ((u16*)out)[((size_t)(rr * 256 + m)) * 768 + (size_t)z * 96 + d] = f2bf(val);
        } else if constexpr (EPI == 8) {
          const int buf = n / 768, col = n - buf * 768;
          ((u16*)out)[(size_t)buf * 12582912 + (size_t)m * 768 + col] = f2bf(val + bz);
        }
      }
    }
  }
}

// ---------------- row softmax fused with split-K reduce ----------------
__global__ __launch_bounds__(256) void softmax_row(const float* __restrict__ part,
                                                   float* __restrict__ probs_f,
                                                   u16* __restrict__ probs_b) {
  const int wid = threadIdx.x >> 6, lane = threadIdx.x & 63;
  const int row = blockIdx.x * 4 + wid;
  const int h = row >> 8, i = row & 255;
  const size_t base = (size_t)h * 16 * 65536 + (size_t)i * 256 + lane * 4;
  floatx4 v = (floatx4){0.f, 0.f, 0.f, 0.f};
#pragma unroll
  for (int s16 = 0; s16 < 16; ++s16) {
    floatx4 p = *(const floatx4*)(part + base + (size_t)s16 * 65536);
#pragma unroll
    for (int j = 0; j < 4; ++j) v[j] += p[j];
  }
  float mx = fmaxf(fmaxf(v[0], v[1]), fmaxf(v[2], v[3]));
#pragma unroll
  for (int m = 1; m < 64; m <<= 1) mx = fmaxf(mx, __shfl_xor(mx, m));
  float e[4], s = 0.f;
#pragma unroll
  for (int j = 0; j < 4; ++j) { e[j] = __expf(v[j] - mx); s += e[j]; }
#pragma unroll
  for (int m = 1; m < 64; m <<= 1) s += __shfl_xor(s, m);
  const float inv = 1.f / s;
  floatx4 of;
  short4v ob;
#pragma unroll
  for (int j = 0; j < 4; ++j) {
    const float p = e[j] * inv;
    of[j] = p;
    ob[j] = (short)f2bf(p);
  }
  *(floatx4*)(probs_f + (size_t)row * 256 + lane * 4) = of;
  *(short4v*)(probs_b + (size_t)row * 256 + lane * 4) = ob;
}

// ---------------- pack V^T for row-attn PV: vt[h][(r*96+d)][j] = v[(r*256+j)*768+h*96+d]
__global__ __launch_bounds__(256) void pack_vt(const u16* __restrict__ v, u16* __restrict__ vt) {
  __shared__ u16 S[64][104];  // [j][d], padded
  const int jb = blockIdx.x, r = blockIdx.y, h = blockIdx.z;
  const int t = threadIdx.x;
#pragma unroll
  for (int p = 0; p < 3; ++p) {
    const int cid = t + p * 256;
    const int j = cid / 12, ch = cid - j * 12;
    short8 x = *(const short8*)&v[((size_t)(r * 256 + jb * 64 + j)) * 768 + h * 96 + ch * 8];
    *(short8*)&S[j][ch * 8] = x;
  }
  __syncthreads();
#pragma unroll
  for (int p = 0; p < 3; ++p) {
    const int cid = t + p * 256;
    const int d = cid / 8, cj = cid - d * 8;
    u16 tmp[8];
#pragma unroll
    for (int m = 0; m < 8; ++m) tmp[m] = S[cj * 8 + m][d];
    *(short8*)&vt[((size_t)(h * 6144 + r * 96 + d)) * 256 + jb * 64 + cj * 8] = *(short8*)tmp;
  }
}

// ---------------- fused column attention: one block per (c, h) ----------------
__global__ __launch_bounds__(256) void col_attn(const u16* __restrict__ q,
                                                const u16* __restrict__ k,
                                                const u16* __restrict__ v,
                                                float* __restrict__ probs,
                                                u16* __restrict__ ctx) {
  __shared__ u16 qs[64][104];
  __shared__ u16 ks[64][104];
  __shared__ u16 vt[96][72];
  __shared__ u16 ps[64][72];
  const int c = blockIdx.x, h = blockIdx.y;
  const int t = threadIdx.x;
#pragma unroll
  for (int p = 0; p < 3; ++p) {
    const int cid = t + p * 256;
    const int i = cid / 12, ch = cid - i * 12;
    const size_t g = ((size_t)(i * 256 + c)) * 768 + h * 96 + ch * 8;
    short8 qv = *(const short8*)(q + g);
    short8 kv = *(const short8*)(k + g);
    short8 vv = *(const short8*)(v + g);
    *(short8*)&qs[i][ch * 8] = qv;
    *(short8*)&ks[i][ch * 8] = kv;
#pragma unroll
    for (int m = 0; m < 8; ++m) vt[ch * 8 + m][i] = (u16)vv[m];
  }
  __syncthreads();
  const int lane = t & 63, wid = t >> 6;
  const int lrow = lane & 15, lhi = lane >> 4;

  floatx4 s[4];
#pragma unroll
  for (int nj = 0; nj < 4; ++nj) s[nj] = (floatx4){0.f, 0.f, 0.f, 0.f};
#pragma unroll
  for (int kk = 0; kk < 3; ++kk) {
    short8 a = *(const short8*)&qs[wid * 16 + lrow][kk * 32 + lhi * 8];
#pragma unroll
    for (int nj = 0; nj < 4; ++nj) {
      short8 bb = *(const short8*)&ks[nj * 16 + lrow][kk * 32 + lhi * 8];
      s[nj] = __builtin_amdgcn_mfma_f32_16x16x32_bf16(a, bb, s[nj], 0, 0, 0);
    }
  }
  const size_t pb = ((size_t)(h * 256 + c)) * 4096;
#pragma unroll
  for (int r4 = 0; r4 < 4; ++r4) {
    float mx = fmaxf(fmaxf(s[0][r4], s[1][r4]), fmaxf(s[2][r4], s[3][r4]));
    mx = fmaxf(mx, __shfl_xor(mx, 1));
    mx = fmaxf(mx, __shfl_xor(mx, 2));
    mx = fmaxf(mx, __shfl_xor(mx, 4));
    mx = fmaxf(mx, __shfl_xor(mx, 8));
    float e[4], sum = 0.f;
#pragma unroll
    for (int nj = 0; nj < 4; ++nj) { e[nj] = __expf(s[nj][r4] - mx); sum += e[nj]; }
    sum += __shfl_xor(sum, 1);
    sum += __shfl_xor(sum, 2);
    sum += __shfl_xor(sum, 4);
    sum += __shfl_xor(sum, 8);
    const float inv = 1.f / sum;
    const int i = wid * 16 + lhi * 4 + r4;
#pragma unroll
    for (int nj = 0; nj < 4; ++nj) {
      const float pv = e[nj] * inv;
      const int j = nj * 16 + lrow;
      probs[pb + (size_t)i * 64 + j] = pv;
      ps[i][j] = f2bf(pv);
    }
  }
  __syncthreads();
  floatx4 o[6];
#pragma unroll
  for (int df = 0; df < 6; ++df) o[df] = (floatx4){0.f, 0.f, 0.f, 0.f};
#pragma unroll
  for (int k2 = 0; k2 < 2; ++k2) {
    short8 a = *(const short8*)&ps[wid * 16 + lrow][k2 * 32 + lhi * 8];
#pragma unroll
    for (int df = 0; df < 6; ++df) {
      short8 bb = *(const short8*)&vt[df * 16 + lrow][k2 * 32 + lhi * 8];
      o[df] = __builtin_amdgcn_mfma_f32_16x16x32_bf16(a, bb, o[df], 0, 0, 0);
    }
  }
#pragma unroll
  for (int df = 0; df < 6; ++df)
#pragma unroll
    for (int r4 = 0; r4 < 4; ++r4) {
      const int i = wid * 16 + lhi * 4 + r4;
      const int d = df * 16 + lrow;
      ctx[((size_t)(i * 256 + c)) * 768 + h * 96 + d] = f2bf(o[df][r4]);
    }
}

// ---------------- host launch ----------------
extern "C" void kernel_launch(void* const* d_in, const int* in_sizes, int n_in,
                              void* d_out, int out_size, void* d_ws, size_t ws_size,
                              hipStream_t stream) {
  const float* x_in  = (const float*)d_in[0];
  const float* lnr_w = (const float*)d_in[1];
  const float* lnr_b = (const float*)d_in[2];
  const float* rq_w  = (const float*)d_in[3];
  const float* rq_b  = (const float*)d_in[4];
  const float* rk_w  = (const float*)d_in[5];
  const float* rk_b  = (const float*)d_in[6];
  const float* rv_w  = (const float*)d_in[7];
  const float* rv_b  = (const float*)d_in[8];
  const float* ro_w  = (const float*)d_in[9];
  const float* ro_b  = (const float*)d_in[10];
  const float* lnc_w = (const float*)d_in[11];
  const float* lnc_b = (const float*)d_in[12];
  const float* cq_w  = (const float*)d_in[13];
  const float* cq_b  = (const float*)d_in[14];
  const float* ck_w  = (const float*)d_in[15];
  const float* ck_b  = (const float*)d_in[16];
  const float* cv_w  = (const float*)d_in[17];
  const float* cv_b  = (const float*)d_in[18];
  const float* co_w  = (const float*)d_in[19];
  const float* co_b  = (const float*)d_in[20];
  const float* lnf_w = (const float*)d_in[21];
  const float* lnf_b = (const float*)d_in[22];
  const float* f1_w  = (const float*)d_in[23];
  const float* f1_b  = (const float*)d_in[24];
  const float* f2_w  = (const float*)d_in[25];
  const float* f2_b  = (const float*)d_in[26];

  const float s_row = 0.0127577591f;  // (96^-0.5)/8
  const float s_col = 0.1020620726f;  // 96^-0.5

  // ---- ws layout ----
  char* ws = (char*)d_ws;
  const size_t WSZ_E = 589824 * 2;        // one E x E bf16 weight
  u16* w_all = (u16*)ws;                  // rq,rk,rv | ro | cq,ck,cv | co | f1 | f2
  u16* w_rqkv = w_all;
  u16* w_ro   = (u16*)(ws + 3 * WSZ_E);
  u16* w_cqkv = (u16*)(ws + 4 * WSZ_E);
  u16* w_co   = (u16*)(ws + 7 * WSZ_E);
  u16* w_f1   = (u16*)(ws + 8 * WSZ_E);                 // 4,718,592 B
  u16* w_f2   = (u16*)(ws + 8 * WSZ_E + 4718592);       // 4,718,592 B
  size_t off = 8 * WSZ_E + 2 * 4718592;                 // 18,874,368

  const bool xf32 = ws_size >= 147849216ULL;            // f32 residual if it fits
  char* x_cur = ws + off;                               // f32 (50.3MB) or bf16 (25.2MB)
  off += xf32 ? 50331648 : 25165824;
  u16* qb = (u16*)(ws + off); off += 25165824;
  u16* kb = (u16*)(ws + off); off += 25165824;
  u16* vb = (u16*)(ws + off); off += 25165824;
  u16* probsb = (u16*)(ws + off); off += 1048576;       // bf16 row probs
  float* qkvb_row = (float*)(ws + off); off += 9216;    // [2304] f32
  float* qkvb_col = (float*)(ws + off); off += 9216;

  u16* vt     = qb;            // row-attn V^T overlays qb (free after logits)
  u16* ctx1   = kb;            // row-attn context overlays kb
  u16* hidden = qb;            // FFN hidden chunk (50.3MB) overlays qb+kb
  u16* xn3    = vb;            // stage-3 LN output overlays vb

  // ---- d_out layout + d_out-as-scratch ----
  float* out_x  = (float*)d_out;            // 12,582,912 f32 (free until final fc2)
  float* out_rp = out_x + 12582912;         // row_probs [8,1,256,256] f32
  float* out_cp = out_x + 13107200;         // col_probs [8,256,1,64,64] f32
  u16* xn   = (u16*)out_x;                  // LN out (stages 1,2), lower half of out_x
  u16* ctx2 = (u16*)((char*)out_x + 25165824);  // col-attn context, upper half
  float* part = out_x;                      // split-K logits partials (33.5MB, dead after softmax)

  const dim3 blk(256);

  // ---- weight conversion (one dispatch) + bias packs ----
  CvtArgs ca;
  ca.src[0] = rq_w; ca.src[1] = rk_w; ca.src[2] = rv_w; ca.src[3] = ro_w;
  ca.src[4] = cq_w; ca.src[5] = ck_w; ca.src[6] = cv_w; ca.src[7] = co_w;
  ca.src[8] = f1_w; ca.src[9] = f2_w;
  for (int i = 0; i < 10; ++i) ca.scale[i] = 1.f;
  ca.scale[0] = s_row; ca.scale[4] = s_col;
  cvt_all<<<9216, blk, 0, stream>>>(ca, w_all);
  bias_pack<<<9, blk, 0, stream>>>(rq_b, rk_b, rv_b, s_row, qkvb_row);
  bias_pack<<<9, blk, 0, stream>>>(cq_b, ck_b, cv_b, s_col, qkvb_col);

  // ---- Stage 1: row attention ----
  ln_kernel<true><<<4096, blk, 0, stream>>>(x_in, lnr_w, lnr_b, xn);
  gemm_bt<0, 8><<<dim3(128, 18, 1), blk, 0, stream>>>(xn, w_rqkv, qkvb_row, nullptr, qb, 768, 768, 768, 0, 0, 0, 768, 1.f);
  // split-K logits: grid.z = h*16+s, partials into d_out scratch (xn is dead now)
  gemm_bt<2, 1><<<dim3(2, 2, 128), blk, 0, stream>>>(qb, kb, nullptr, nullptr, part, 384, 0, 0, 0, 0, 65536LL, 256, 1.f);
  softmax_row<<<512, blk, 0, stream>>>(part, out_rp, probsb);
  pack_vt<<<dim3(4, 64, 8), blk, 0, stream>>>(vb, vt);
  gemm_bt<0, 7><<<dim3(2, 48, 8), blk, 0, stream>>>(probsb, vt, nullptr, nullptr, ctx1, 256, 256, 256, 65536LL, 1572864LL, 0, 0, 1.f);
  if (xf32)
    gemm_bt<0, 3><<<dim3(128, 6, 1), blk, 0, stream>>>(ctx1, w_ro, ro_b, x_in, x_cur, 768, 768, 768, 0, 0, 0, 768, 1.f);
  else
    gemm_bt<0, 4><<<dim3(128, 6, 1), blk, 0, stream>>>(ctx1, w_ro, ro_b, x_in, x_cur, 768, 768, 768, 0, 0, 0, 768, 1.f);

  // ---- Stage 2: column attention ----
  if (xf32) ln_kernel<true><<<4096, blk, 0, stream>>>(x_cur, lnc_w, lnc_b, xn);
  else      ln_kernel<false><<<4096, blk, 0, stream>>>(x_cur, lnc_w, lnc_b, xn);
  gemm_bt<0, 8><<<dim3(128, 18, 1), blk, 0, stream>>>(xn, w_cqkv, qkvb_col, nullptr, qb, 768, 768, 768, 0, 0, 0, 768, 1.f);
  col_attn<<<dim3(256, 8), blk, 0, stream>>>(qb, kb, vb, out_cp, ctx2);
  if (xf32)
    gemm_bt<0, 3><<<dim3(128, 6, 1), blk, 0, stream>>>(ctx2, w_co, co_b, x_cur, x_cur, 768, 768, 768, 0, 0, 0, 768, 1.f);
  else
    gemm_bt<0, 6><<<dim3(128, 6, 1), blk, 0, stream>>>(ctx2, w_co, co_b, x_cur, x_cur, 768, 768, 768, 0, 0, 0, 768, 1.f);

  // ---- Stage 3: FFN (F chunked 2x1536 so hidden fits qb+kb) ----
  if (xf32) ln_kernel<true><<<4096, blk, 0, stream>>>(x_cur, lnf_w, lnf_b, xn3);
  else      ln_kernel<false><<<4096, blk, 0, stream>>>(x_cur, lnf_w, lnf_b, xn3);
  // chunk 0
  gemm_bt<0, 2><<<dim3(128, 12, 1), blk, 0, stream>>>(xn3, w_f1, f1_b, nullptr, hidden, 768, 768, 768, 0, 0, 0, 1536, 1.f);
  if (xf32)
    gemm_bt<0, 3><<<dim3(128, 6, 1), blk, 0, stream>>>(hidden, w_f2, f2_b, x_cur, out_x, 1536, 1536, 3072, 0, 0, 0, 768, 1.f);
  else
    gemm_bt<0, 5><<<dim3(128, 6, 1), blk, 0, stream>>>(hidden, w_f2, f2_b, x_cur, out_x, 1536, 1536, 3072, 0, 0, 0, 768, 1.f);
  // chunk 1 (accumulate into out_x)
  gemm_bt<0, 2><<<dim3(128, 12, 1), blk, 0, stream>>>(xn3, w_f1 + 1536 * 768, f1_b + 1536, nullptr, hidden, 768, 768, 768, 0, 0, 0, 1536, 1.f);
  gemm_bt<0, 3><<<dim3(128, 6, 1), blk, 0, stream>>>(hidden, w_f2 + 1536, nullptr, out_x, out_x, 1536, 1536, 3072, 0, 0, 0, 768, 1.f);
}

// Round 14
// 618.945 us; speedup vs baseline: 1.6340x; 1.0837x over previous
//
#include <hip/hip_runtime.h>
#include <cstdint>

typedef unsigned short u16;
typedef __attribute__((ext_vector_type(8))) short short8;   // 8 x bf16 (4 VGPR)
typedef __attribute__((ext_vector_type(4))) short short4v;  // 4 x bf16
typedef __attribute__((ext_vector_type(4))) float floatx4;  // MFMA acc / float4

#define DEV __device__ __forceinline__

DEV float bf2f(u16 u) { union { uint32_t i; float f; } w; w.i = ((uint32_t)u) << 16; return w.f; }
DEV u16 f2bf(float f) {
  union { float f; uint32_t i; } w; w.f = f;
  uint32_t x = w.i;
  return (u16)((x + 0x7fffu + ((x >> 16) & 1u)) >> 16);  // RNE
}

// fast exact-gelu: A&S 7.1.26 erf approx, |err|<=1.5e-7, branchless
DEV float fast_gelu(float x) {
  const float y = x * 0.70710678118f;
  const float ay = fabsf(y);
  const float t = 1.f / (1.f + 0.3275911f * ay);
  const float poly = t * (0.254829592f + t * (-0.284496736f +
                     t * (1.421413741f + t * (-1.453152027f + t * 1.061405429f))));
  const float er = 1.f - poly * __expf(-y * y);
  const float erf_y = __builtin_copysignf(er, y);
  return 0.5f * x * (1.f + erf_y);
}

// async global->LDS, 16B per lane. LDS dest must be wave-uniform base; HW adds lane*16.
DEV void async_copy16(const u16* g, u16* l) {
  __builtin_amdgcn_global_load_lds(
      (const __attribute__((address_space(1))) void*)(uintptr_t)g,
      (__attribute__((address_space(3))) void*)(uint32_t)(uintptr_t)l,
      16, 0, 0);
}

// ---------------- fused f32 -> bf16 weight convert, PACKED chunk-major ----------------
// Packed layout per weight (N rows x K cols): tile(nt,kt) = 128 rows x 32 k,
// flat = (nt*(K/32)+kt)*4096 + c*1024 + row128*8 + (k&7), c=(k>>3)&3.
// Regions at same base offsets as row-major (equal sizes): 8 x 768x768, f1 3072x768, f2 768x3072.
struct CvtArgs {
  const float* src[10];
  float scale[10];
};
__global__ __launch_bounds__(256) void cvt_all(CvtArgs a, u16* __restrict__ dst) {
  const size_t e = ((size_t)blockIdx.x * 256 + threadIdx.x) * 4;  // packed dest offset
  if (e >= 9437184) return;
  int reg, N, K;
  size_t base;
  if (e < 4718592) { reg = (int)(e / 589824); base = (size_t)reg * 589824; N = 768; K = 768; }
  else if (e < 7077888) { reg = 8; base = 4718592; N = 3072; K = 768; }
  else { reg = 9; base = 7077888; N = 768; K = 3072; }
  const int NKT = K >> 5;
  const size_t r = e - base;
  const int tile = (int)(r >> 12);
  const int nt = tile / NKT, kt = tile - nt * NKT;
  const int rem = (int)(r & 4095);
  const int c = rem >> 10, row = (rem >> 3) & 127, j = rem & 7;  // j in {0,4}
  const int n = nt * 128 + row, k = kt * 32 + c * 8 + j;
  const float sc = a.scale[reg];
  floatx4 f = *(const floatx4*)(a.src[reg] + (size_t)n * K + k);
  short4v o;
#pragma unroll
  for (int q = 0; q < 4; ++q) o[q] = (short)f2bf(f[q] * sc);
  *(short4v*)(dst + e) = o;
}

// pack q/k/v biases into one [2304] f32 buffer per stage, q part pre-scaled
__global__ __launch_bounds__(256) void bias_pack(const float* __restrict__ qb,
                                                 const float* __restrict__ kb,
                                                 const float* __restrict__ vb,
                                                 float sq, float* __restrict__ out) {
  const int i = blockIdx.x * 256 + threadIdx.x;
  if (i >= 2304) return;
  const int buf = i / 768, c = i - buf * 768;
  out[i] = buf == 0 ? qb[c] * sq : (buf == 1 ? kb[c] : vb[c]);
}

// ---------------- LayerNorm: one wave per row of 768, bf16 out ----------------
template<bool INF32>
__global__ __launch_bounds__(256) void ln_kernel(const void* __restrict__ in,
                                                 const float* __restrict__ w,
                                                 const float* __restrict__ b,
                                                 u16* __restrict__ out) {
  const int wid = threadIdx.x >> 6, lane = threadIdx.x & 63;
  const int row = blockIdx.x * 4 + wid;  // 16384 rows
  const size_t base = (size_t)row * 768;
  float v[12];
#pragma unroll
  for (int p = 0; p < 3; ++p) {
    const int e = p * 256 + lane * 4;
    if constexpr (INF32) {
      floatx4 f = *(const floatx4*)((const float*)in + base + e);
#pragma unroll
      for (int j = 0; j < 4; ++j) v[p * 4 + j] = f[j];
    } else {
      short4v u = *(const short4v*)((const u16*)in + base + e);
#pragma unroll
      for (int j = 0; j < 4; ++j) v[p * 4 + j] = bf2f((u16)u[j]);
    }
  }
  float s = 0.f, sq = 0.f;
#pragma unroll
  for (int i = 0; i < 12; ++i) { s += v[i]; sq += v[i] * v[i]; }
#pragma unroll
  for (int m = 1; m < 64; m <<= 1) { s += __shfl_xor(s, m); sq += __shfl_xor(sq, m); }
  const float mean = s * (1.f / 768.f);
  const float var = sq * (1.f / 768.f) - mean * mean;
  const float rstd = rsqrtf(var + 1e-5f);
#pragma unroll
  for (int p = 0; p < 3; ++p) {
    const int e = p * 256 + lane * 4;
    floatx4 wv = *(const floatx4*)(w + e);
    floatx4 bv = *(const floatx4*)(b + e);
    short4v o;
#pragma unroll
    for (int j = 0; j < 4; ++j) {
      float y = (v[p * 4 + j] - mean) * rstd * wv[j] + bv[j];
      o[j] = (short)f2bf(y);
    }
    *(short4v*)(out + base + e) = o;
  }
}

// ---------------- GEMM: C[M,N] = A[M,K] * B[N,K]^T (+epilogue) ----------------
// 128x128 tile, BK=32, 4 waves (2x2), mfma_f32_16x16x32_bf16.
// Round-8 proven pipeline: 3-buffer LDS rotation, stage(kt+2) -> compute(kt) ->
// counted vmcnt(4) -> raw s_barrier, setprio around MFMA.
// BP=1: B operand is PRE-PACKED chunk-major in global memory -> staging is a
// linear 1KB DMA per instruction (coalesced) AND frag reads are conflict-free
// (r10-proven bank pattern: 16 lanes x 16B at row*16B stride = 2-way, free).
// BP=0: round-8 row-major B path (used for logits where B is an activation).
// AMODE: 0 = normal strides lda/ldb
//        2 = split-K row-attn logits: z = h*16+s, head h, K-window [s*384,+384)
// EPI: 1 f32=acc | 2 bf16=gelu(acc+bz) | 3 f32=resf32+acc+bz | 4 bf16=resf32+acc+bz
//      5 f32=resbf16+acc+bz | 6 bf16=resbf16+acc+bz
//      7 bf16 scatter (row-attn PV): n=(r*96+d) -> out[(r*256+m)*768 + z*96 + d]
//      8 bf16 merged-QKV split write: buf=n/768 -> out + buf*12582912 + m*768 + (n%768)
template<int AMODE, int BP>
DEV void stage_tile(const u16* __restrict__ Ab, const u16* __restrict__ Bsrc,
                    int m0, int n0, int lda, int ldb, int kk0, int ktAbs, int t,
                    u16* ldsA, u16* ldsB) {
  const int wid = t >> 6, lane = t & 63;
  // A staging: swizzled source col (paired with read-side lhi^swl XOR, r8-verified)
  const int col = (((t & 3) ^ ((t >> 2) & 3)) << 3);
#pragma unroll
  for (int i = 0; i < 2; ++i) {
    const int r = i * 64 + (t >> 2);
    const int kk = kk0 + col;
    const u16* ga;
    if constexpr (AMODE == 0) {
      ga = Ab + (size_t)(m0 + r) * lda + kk;
    } else {
      const int r96 = kk / 96, d = kk - r96 * 96;  // 8|96: chunk never crosses r96
      ga = Ab + (size_t)r96 * 196608 + (size_t)(m0 + r) * 768 + d;
    }
    async_copy16(ga, ldsA + i * 2048 + wid * 512);

    const int slot = i * 4 + wid;
    if constexpr (BP) {
      // linear 1KB copy from packed global tile
      const u16* gb = Bsrc + (size_t)ktAbs * 4096 + slot * 512 + lane * 8;
      async_copy16(gb, ldsB + slot * 512);
    } else {
      const u16* gb;
      if constexpr (AMODE == 0) {
        gb = Bsrc + (size_t)(n0 + r) * ldb + kk;
      } else {
        const int r96 = kk / 96, d = kk - r96 * 96;
        gb = Bsrc + (size_t)r96 * 196608 + (size_t)(n0 + r) * 768 + d;
      }
      async_copy16(gb, ldsB + i * 2048 + wid * 512);
    }
  }
}

template<int AMODE, int EPI, int BP>
__global__ __launch_bounds__(256) void gemm_bt(
    const u16* __restrict__ A, const u16* __restrict__ B,
    const float* __restrict__ bias, const void* __restrict__ res,
    void* __restrict__ out, int K, int lda, int ldb,
    long long aBatch, long long bBatch, long long outBatch, int ldc, int bkt0,
    float scale) {
  __shared__ u16 lds[3 * 8192];  // 3 x (A 128x32 + B 128x32) = 48KB
  const int t = threadIdx.x;
  const int z = blockIdx.z;
  const int m0 = blockIdx.x * 128, n0 = blockIdx.y * 128;
  const u16* Ab;
  const u16* Bb;
  int koff = 0;
  if constexpr (AMODE == 0) { Ab = A + (size_t)z * aBatch; Bb = B + (size_t)z * bBatch; }
  else { const int h = z >> 4; Ab = A + h * 96; Bb = B + h * 96; koff = (z & 15) * 384; }

  // BP: fold n-tile and k-tile-window into the B stage base; ldb = NKT (K_total/32)
  const u16* Bstage;
  if constexpr (BP) Bstage = Bb + ((size_t)((n0 >> 7) * ldb + bkt0)) * 4096;
  else Bstage = Bb;

  const int wid = t >> 6, lane = t & 63;
  const int wr = wid >> 1, wc = wid & 1;
  const int lrow = lane & 15, lhi = lane >> 4;
  const int swl = lrow & 3;  // A read-side swizzle key (matches stage-side col xor)

  floatx4 acc[4][4];
#pragma unroll
  for (int i = 0; i < 4; ++i)
#pragma unroll
    for (int j = 0; j < 4; ++j) acc[i][j] = (floatx4){0.f, 0.f, 0.f, 0.f};

  const int NT = K >> 5;  // K/32 tiles (all K are multiples of 32)

  // prologue: stage tiles 0 and 1
  stage_tile<AMODE, BP>(Ab, Bstage, m0, n0, lda, ldb, koff, 0, t, lds, lds + 4096);
  if (NT > 1)
    stage_tile<AMODE, BP>(Ab, Bstage, m0, n0, lda, ldb, koff + 32, 1, t,
                          lds + 8192, lds + 8192 + 4096);
  if (NT > 2) asm volatile("s_waitcnt vmcnt(4)" ::: "memory");
  else        asm volatile("s_waitcnt vmcnt(0)" ::: "memory");
  __builtin_amdgcn_s_barrier();
  asm volatile("" ::: "memory");

  int cur = 0, nxt = 2;
  for (int kt = 0; kt < NT; ++kt) {
    const bool more = (kt + 2) < NT;
    if (more)
      stage_tile<AMODE, BP>(Ab, Bstage, m0, n0, lda, ldb, koff + (kt + 2) * 32, kt + 2, t,
                            lds + nxt * 8192, lds + nxt * 8192 + 4096);

    const u16* lA = lds + cur * 8192;
    const u16* lB = lA + 4096;
    short8 af[4], bfr[4];
#pragma unroll
    for (int mi = 0; mi < 4; ++mi)
      af[mi] = *(const short8*)&lA[(wr * 64 + mi * 16 + lrow) * 32 + ((lhi ^ swl) << 3)];
#pragma unroll
    for (int ni = 0; ni < 4; ++ni) {
      if constexpr (BP)
        bfr[ni] = *(const short8*)&lB[lhi * 1024 + (wc * 64 + ni * 16 + lrow) * 8];
      else
        bfr[ni] = *(const short8*)&lB[(wc * 64 + ni * 16 + lrow) * 32 + ((lhi ^ swl) << 3)];
    }

    __builtin_amdgcn_s_setprio(1);
#pragma unroll
    for (int mi = 0; mi < 4; ++mi)
#pragma unroll
      for (int ni = 0; ni < 4; ++ni)
        acc[mi][ni] = __builtin_amdgcn_mfma_f32_16x16x32_bf16(af[mi], bfr[ni], acc[mi][ni], 0, 0, 0);
    __builtin_amdgcn_s_setprio(0);

    if (kt + 1 < NT) {
      if (more) asm volatile("s_waitcnt vmcnt(4)" ::: "memory");  // kt+1 landed, kt+2 in flight
      else      asm volatile("s_waitcnt vmcnt(0)" ::: "memory");  // tail drain
      __builtin_amdgcn_s_barrier();
      asm volatile("" ::: "memory");
    }
    cur = (cur == 2) ? 0 : cur + 1;
    nxt = (nxt == 2) ? 0 : nxt + 1;
  }

  const int mbase = m0 + wr * 64;
  const int nbase = n0 + wc * 64;
#pragma unroll
  for (int mi = 0; mi < 4; ++mi) {
#pragma unroll
    for (int ni = 0; ni < 4; ++ni) {
      const int n = nbase + ni * 16 + lrow;
      float bz = 0.f;
      if constexpr (EPI != 1 && EPI != 7) { if (bias) bz = bias[n]; }
#pragma unroll
      for (int r4 = 0; r4 < 4; ++r4) {
        const int m = mbase + mi * 16 + lhi * 4 + r4;
        const float val = acc[mi][ni][r4];
        if constexpr (EPI == 1) {
          ((float*)out)[(size_t)z * outBatch + (size_t)m * ldc + n] = val;
        } else if constexpr (EPI == 2) {
          ((u16*)out)[(size_t)m * ldc + n] = f2bf(fast_gelu(val + bz));
        } else if constexpr (EPI == 3) {
          const float r = ((const float*)res)[(size_t)m * ldc + n];
          ((float*)out)[(size_t)m * ldc + n] = r + val + bz;
        } else if constexpr (EPI == 4) {
          const float r = ((const float*)res)[(size_t)m * ldc + n];
          ((u16*)out)[(size_t)m * ldc + n] = f2bf(r + val + bz);
        } else if constexpr (EPI == 5) {
          const float r = bf2f(((const u16*)res)[(size_t)m * ldc + n]);
          ((float*)out)[(size_t)m * ldc + n] = r + val + bz;
        } else if constexpr (EPI == 6) {
          const float r = bf2f(((const u16*)res)[(size_t)m * ldc + n]);
          ((u16*)out)[(size_t)m * ldc + n] = f2bf(r + val + bz);
        } else if constexpr (EPI == 7) {
          const int rr = n / 96, d = n - rr * 96;
          ((u16*)out)[((size_t)(rr * 256 + m)) * 768 + (size_t)z * 96 + d] = f2bf(val);
        } else if constexpr (EPI == 8) {
          const int buf = n / 768, col = n - buf * 768;
          ((u16*)out)[(size_t)buf * 12582912 + (size_t)m * 768 + col] = f2bf(val + bz);
        }
      }
    }
  }
}

// ---------------- row softmax fused with split-K reduce ----------------
__global__ __launch_bounds__(256) void softmax_row(const float* __restrict__ part,
                                                   float* __restrict__ probs_f,
                                                   u16* __restrict__ probs_b) {
  const int wid = threadIdx.x >> 6, lane = threadIdx.x & 63;
  const int row = blockIdx.x * 4 + wid;
  const int h = row >> 8, i = row & 255;
  const size_t base = (size_t)h * 16 * 65536 + (size_t)i * 256 + lane * 4;
  floatx4 v = (floatx4){0.f, 0.f, 0.f, 0.f};
#pragma unroll
  for (int s16 = 0; s16 < 16; ++s16) {
    floatx4 p = *(const floatx4*)(part + base + (size_t)s16 * 65536);
#pragma unroll
    for (int j = 0; j < 4; ++j) v[j] += p[j];
  }
  float mx = fmaxf(fmaxf(v[0], v[1]), fmaxf(v[2], v[3]));
#pragma unroll
  for (int m = 1; m < 64; m <<= 1) mx = fmaxf(mx, __shfl_xor(mx, m));
  float e[4], s = 0.f;
#pragma unroll
  for (int j = 0; j < 4; ++j) { e[j] = __expf(v[j] - mx); s += e[j]; }
#pragma unroll
  for (int m = 1; m < 64; m <<= 1) s += __shfl_xor(s, m);
  const float inv = 1.f / s;
  floatx4 of;
  short4v ob;
#pragma unroll
  for (int j = 0; j < 4; ++j) {
    const float p = e[j] * inv;
    of[j] = p;
    ob[j] = (short)f2bf(p);
  }
  *(floatx4*)(probs_f + (size_t)row * 256 + lane * 4) = of;
  *(short4v*)(probs_b + (size_t)row * 256 + lane * 4) = ob;
}

// ---------------- pack V^T for row-attn PV, PACKED chunk-major ----------------
// logical vt[h][row=(r*96+d)][k=jb*64+cj*8] -> packed per h (N=6144,K=256,NKT=8):
// off = h*1572864 + ((row>>7)*8 + (k>>5))*4096 + ((k>>3)&3)*1024 + (row&127)*8
__global__ __launch_bounds__(256) void pack_vt(const u16* __restrict__ v, u16* __restrict__ vt) {
  __shared__ u16 S[64][104];  // [j][d], padded
  const int jb = blockIdx.x, r = blockIdx.y, h = blockIdx.z;
  const int t = threadIdx.x;
#pragma unroll
  for (int p = 0; p < 3; ++p) {
    const int cid = t + p * 256;
    const int j = cid / 12, ch = cid - j * 12;
    short8 x = *(const short8*)&v[((size_t)(r * 256 + jb * 64 + j)) * 768 + h * 96 + ch * 8];
    *(short8*)&S[j][ch * 8] = x;
  }
  __syncthreads();
#pragma unroll
  for (int p = 0; p < 3; ++p) {
    const int cid = t + p * 256;
    const int d = cid / 8, cj = cid - d * 8;
    u16 tmp[8];
#pragma unroll
    for (int m = 0; m < 8; ++m) tmp[m] = S[cj * 8 + m][d];
    const int row_t = r * 96 + d;
    const int k = jb * 64 + cj * 8;
    const size_t off = (size_t)h * 1572864 +
                       ((size_t)((row_t >> 7) * 8 + (k >> 5))) * 4096 +
                       ((k >> 3) & 3) * 1024 + (row_t & 127) * 8;
    *(short8*)&vt[off] = *(short8*)tmp;
  }
}

// ---------------- fused column attention: one block per (c, h) ----------------
__global__ __launch_bounds__(256) void col_attn(const u16* __restrict__ q,
                                                const u16* __restrict__ k,
                                                const u16* __restrict__ v,
                                                float* __restrict__ probs,
                                                u16* __restrict__ ctx) {
  __shared__ u16 qs[64][104];
  __shared__ u16 ks[64][104];
  __shared__ u16 vt[96][72];
  __shared__ u16 ps[64][72];
  const int c = blockIdx.x, h = blockIdx.y;
  const int t = threadIdx.x;
#pragma unroll
  for (int p = 0; p < 3; ++p) {
    const int cid = t + p * 256;
    const int i = cid / 12, ch = cid - i * 12;
    const size_t g = ((size_t)(i * 256 + c)) * 768 + h * 96 + ch * 8;
    short8 qv = *(const short8*)(q + g);
    short8 kv = *(const short8*)(k + g);
    short8 vv = *(const short8*)(v + g);
    *(short8*)&qs[i][ch * 8] = qv;
    *(short8*)&ks[i][ch * 8] = kv;
#pragma unroll
    for (int m = 0; m < 8; ++m) vt[ch * 8 + m][i] = (u16)vv[m];
  }
  __syncthreads();
  const int lane = t & 63, wid = t >> 6;
  const int lrow = lane & 15, lhi = lane >> 4;

  floatx4 s[4];
#pragma unroll
  for (int nj = 0; nj < 4; ++nj) s[nj] = (floatx4){0.f, 0.f, 0.f, 0.f};
#pragma unroll
  for (int kk = 0; kk < 3; ++kk) {
    short8 a = *(const short8*)&qs[wid * 16 + lrow][kk * 32 + lhi * 8];
#pragma unroll
    for (int nj = 0; nj < 4; ++nj) {
      short8 bb = *(const short8*)&ks[nj * 16 + lrow][kk * 32 + lhi * 8];
      s[nj] = __builtin_amdgcn_mfma_f32_16x16x32_bf16(a, bb, s[nj], 0, 0, 0);
    }
  }
  const size_t pb = ((size_t)(h * 256 + c)) * 4096;
#pragma unroll
  for (int r4 = 0; r4 < 4; ++r4) {
    float mx = fmaxf(fmaxf(s[0][r4], s[1][r4]), fmaxf(s[2][r4], s[3][r4]));
    mx = fmaxf(mx, __shfl_xor(mx, 1));
    mx = fmaxf(mx, __shfl_xor(mx, 2));
    mx = fmaxf(mx, __shfl_xor(mx, 4));
    mx = fmaxf(mx, __shfl_xor(mx, 8));
    float e[4], sum = 0.f;
#pragma unroll
    for (int nj = 0; nj < 4; ++nj) { e[nj] = __expf(s[nj][r4] - mx); sum += e[nj]; }
    sum += __shfl_xor(sum, 1);
    sum += __shfl_xor(sum, 2);
    sum += __shfl_xor(sum, 4);
    sum += __shfl_xor(sum, 8);
    const float inv = 1.f / sum;
    const int i = wid * 16 + lhi * 4 + r4;
#pragma unroll
    for (int nj = 0; nj < 4; ++nj) {
      const float pv = e[nj] * inv;
      const int j = nj * 16 + lrow;
      probs[pb + (size_t)i * 64 + j] = pv;
      ps[i][j] = f2bf(pv);
    }
  }
  __syncthreads();
  floatx4 o[6];
#pragma unroll
  for (int df = 0; df < 6; ++df) o[df] = (floatx4){0.f, 0.f, 0.f, 0.f};
#pragma unroll
  for (int k2 = 0; k2 < 2; ++k2) {
    short8 a = *(const short8*)&ps[wid * 16 + lrow][k2 * 32 + lhi * 8];
#pragma unroll
    for (int df = 0; df < 6; ++df) {
      short8 bb = *(const short8*)&vt[df * 16 + lrow][k2 * 32 + lhi * 8];
      o[df] = __builtin_amdgcn_mfma_f32_16x16x32_bf16(a, bb, o[df], 0, 0, 0);
    }
  }
#pragma unroll
  for (int df = 0; df < 6; ++df)
#pragma unroll
    for (int r4 = 0; r4 < 4; ++r4) {
      const int i = wid * 16 + lhi * 4 + r4;
      const int d = df * 16 + lrow;
      ctx[((size_t)(i * 256 + c)) * 768 + h * 96 + d] = f2bf(o[df][r4]);
    }
}

// ---------------- host launch ----------------
extern "C" void kernel_launch(void* const* d_in, const int* in_sizes, int n_in,
                              void* d_out, int out_size, void* d_ws, size_t ws_size,
                              hipStream_t stream) {
  const float* x_in  = (const float*)d_in[0];
  const float* lnr_w = (const float*)d_in[1];
  const float* lnr_b = (const float*)d_in[2];
  const float* rq_w  = (const float*)d_in[3];
  const float* rq_b  = (const float*)d_in[4];
  const float* rk_w  = (const float*)d_in[5];
  const float* rk_b  = (const float*)d_in[6];
  const float* rv_w  = (const float*)d_in[7];
  const float* rv_b  = (const float*)d_in[8];
  const float* ro_w  = (const float*)d_in[9];
  const float* ro_b  = (const float*)d_in[10];
  const float* lnc_w = (const float*)d_in[11];
  const float* lnc_b = (const float*)d_in[12];
  const float* cq_w  = (const float*)d_in[13];
  const float* cq_b  = (const float*)d_in[14];
  const float* ck_w  = (const float*)d_in[15];
  const float* ck_b  = (const float*)d_in[16];
  const float* cv_w  = (const float*)d_in[17];
  const float* cv_b  = (const float*)d_in[18];
  const float* co_w  = (const float*)d_in[19];
  const float* co_b  = (const float*)d_in[20];
  const float* lnf_w = (const float*)d_in[21];
  const float* lnf_b = (const float*)d_in[22];
  const float* f1_w  = (const float*)d_in[23];
  const float* f1_b  = (const float*)d_in[24];
  const float* f2_w  = (const float*)d_in[25];
  const float* f2_b  = (const float*)d_in[26];

  const float s_row = 0.0127577591f;  // (96^-0.5)/8
  const float s_col = 0.1020620726f;  // 96^-0.5

  // ---- ws layout ----
  char* ws = (char*)d_ws;
  const size_t WSZ_E = 589824 * 2;        // one E x E bf16 weight (packed, same size)
  u16* w_all = (u16*)ws;                  // rq,rk,rv | ro | cq,ck,cv | co | f1 | f2
  u16* w_rqkv = w_all;
  u16* w_ro   = (u16*)(ws + 3 * WSZ_E);
  u16* w_cqkv = (u16*)(ws + 4 * WSZ_E);
  u16* w_co   = (u16*)(ws + 7 * WSZ_E);
  u16* w_f1   = (u16*)(ws + 8 * WSZ_E);                 // 4,718,592 B
  u16* w_f2   = (u16*)(ws + 8 * WSZ_E + 4718592);       // 4,718,592 B
  size_t off = 8 * WSZ_E + 2 * 4718592;                 // 18,874,368

  const bool xf32 = ws_size >= 147849216ULL;            // f32 residual if it fits
  char* x_cur = ws + off;                               // f32 (50.3MB) or bf16 (25.2MB)
  off += xf32 ? 50331648 : 25165824;
  u16* qb = (u16*)(ws + off); off += 25165824;
  u16* kb = (u16*)(ws + off); off += 25165824;
  u16* vb = (u16*)(ws + off); off += 25165824;
  u16* probsb = (u16*)(ws + off); off += 1048576;       // bf16 row probs
  float* qkvb_row = (float*)(ws + off); off += 9216;    // [2304] f32
  float* qkvb_col = (float*)(ws + off); off += 9216;

  u16* vt     = qb;            // row-attn V^T (packed) overlays qb (free after logits)
  u16* ctx1   = kb;            // row-attn context overlays kb
  u16* hidden = qb;            // FFN hidden chunk (50.3MB) overlays qb+kb
  u16* xn3    = vb;            // stage-3 LN output overlays vb

  // ---- d_out layout + d_out-as-scratch ----
  float* out_x  = (float*)d_out;            // 12,582,912 f32 (free until final fc2)
  float* out_rp = out_x + 12582912;         // row_probs [8,1,256,256] f32
  float* out_cp = out_x + 13107200;         // col_probs [8,256,1,64,64] f32
  u16* xn   = (u16*)out_x;                  // LN out (stages 1,2), lower half of out_x
  u16* ctx2 = (u16*)((char*)out_x + 25165824);  // col-attn context, upper half
  float* part = out_x;                      // split-K logits partials (33.5MB, dead after softmax)

  const dim3 blk(256);

  // ---- weight conversion (one dispatch, packed) + bias packs ----
  CvtArgs ca;
  ca.src[0] = rq_w; ca.src[1] = rk_w; ca.src[2] = rv_w; ca.src[3] = ro_w;
  ca.src[4] = cq_w; ca.src[5] = ck_w; ca.src[6] = cv_w; ca.src[7] = co_w;
  ca.src[8] = f1_w; ca.src[9] = f2_w;
  for (int i = 0; i < 10; ++i) ca.scale[i] = 1.f;
  ca.scale[0] = s_row; ca.scale[4] = s_col;
  cvt_all<<<9216, blk, 0, stream>>>(ca, w_all);
  bias_pack<<<9, blk, 0, stream>>>(rq_b, rk_b, rv_b, s_row, qkvb_row);
  bias_pack<<<9, blk, 0, stream>>>(cq_b, ck_b, cv_b, s_col, qkvb_col);

  // ---- Stage 1: row attention ----
  ln_kernel<true><<<4096, blk, 0, stream>>>(x_in, lnr_w, lnr_b, xn);
  gemm_bt<0, 8, 1><<<dim3(128, 18, 1), blk, 0, stream>>>(xn, w_rqkv, qkvb_row, nullptr, qb, 768, 768, 24, 0, 0, 0, 768, 0, 1.f);
  // split-K logits: grid.z = h*16+s, partials into d_out scratch (xn is dead now)
  gemm_bt<2, 1, 0><<<dim3(2, 2, 128), blk, 0, stream>>>(qb, kb, nullptr, nullptr, part, 384, 0, 0, 0, 0, 65536LL, 256, 0, 1.f);
  softmax_row<<<512, blk, 0, stream>>>(part, out_rp, probsb);
  pack_vt<<<dim3(4, 64, 8), blk, 0, stream>>>(vb, vt);
  gemm_bt<0, 7, 1><<<dim3(2, 48, 8), blk, 0, stream>>>(probsb, vt, nullptr, nullptr, ctx1, 256, 256, 8, 65536LL, 1572864LL, 0, 0, 0, 1.f);
  if (xf32)
    gemm_bt<0, 3, 1><<<dim3(128, 6, 1), blk, 0, stream>>>(ctx1, w_ro, ro_b, x_in, x_cur, 768, 768, 24, 0, 0, 0, 768, 0, 1.f);
  else
    gemm_bt<0, 4, 1><<<dim3(128, 6, 1), blk, 0, stream>>>(ctx1, w_ro, ro_b, x_in, x_cur, 768, 768, 24, 0, 0, 0, 768, 0, 1.f);

  // ---- Stage 2: column attention ----
  if (xf32) ln_kernel<true><<<4096, blk, 0, stream>>>(x_cur, lnc_w, lnc_b, xn);
  else      ln_kernel<false><<<4096, blk, 0, stream>>>(x_cur, lnc_w, lnc_b, xn);
  gemm_bt<0, 8, 1><<<dim3(128, 18, 1), blk, 0, stream>>>(xn, w_cqkv, qkvb_col, nullptr, qb, 768, 768, 24, 0, 0, 0, 768, 0, 1.f);
  col_attn<<<dim3(256, 8), blk, 0, stream>>>(qb, kb, vb, out_cp, ctx2);
  if (xf32)
    gemm_bt<0, 3, 1><<<dim3(128, 6, 1), blk, 0, stream>>>(ctx2, w_co, co_b, x_cur, x_cur, 768, 768, 24, 0, 0, 0, 768, 0, 1.f);
  else
    gemm_bt<0, 6, 1><<<dim3(128, 6, 1), blk, 0, stream>>>(ctx2, w_co, co_b, x_cur, x_cur, 768, 768, 24, 0, 0, 0, 768, 0, 1.f);

  // ---- Stage 3: FFN (F chunked 2x1536 so hidden fits qb+kb) ----
  if (xf32) ln_kernel<true><<<4096, blk, 0, stream>>>(x_cur, lnf_w, lnf_b, xn3);
  else      ln_kernel<false><<<4096, blk, 0, stream>>>(x_cur, lnf_w, lnf_b, xn3);
  // chunk 0  (f1 packed nt-major: chunk offset 1536*768 elems == 12 nt-blocks, works unchanged)
  gemm_bt<0, 2, 1><<<dim3(128, 12, 1), blk, 0, stream>>>(xn3, w_f1, f1_b, nullptr, hidden, 768, 768, 24, 0, 0, 0, 1536, 0, 1.f);
  if (xf32)
    gemm_bt<0, 3, 1><<<dim3(128, 6, 1), blk, 0, stream>>>(hidden, w_f2, f2_b, x_cur, out_x, 1536, 1536, 96, 0, 0, 0, 768, 0, 1.f);
  else
    gemm_bt<0, 5, 1><<<dim3(128, 6, 1), blk, 0, stream>>>(hidden, w_f2, f2_b, x_cur, out_x, 1536, 1536, 96, 0, 0, 0, 768, 0, 1.f);
  // chunk 1 (accumulate into out_x; packed f2 addressed via bkt0=48, NOT pointer offset)
  gemm_bt<0, 2, 1><<<dim3(128, 12, 1), blk, 0, stream>>>(xn3, w_f1 + 1536 * 768, f1_b + 1536, nullptr, hidden, 768, 768, 24, 0, 0, 0, 1536, 0, 1.f);
  gemm_bt<0, 3, 1><<<dim3(128, 6, 1), blk, 0, stream>>>(hidden, w_f2, nullptr, out_x, out_x, 1536, 1536, 96, 0, 0, 0, 768, 48, 1.f);
}